// Round 3
// baseline (71.848 us; speedup 1.0000x reference)
//
#include <hip/hip_runtime.h>
#include <cstdint>

#define BB 4
#define NN 1024
#define DD 32
#define NWORDS 16           // NN / 64
#define RPB 16              // output rows per block
#define BLOCK 1024
#define NEG_INF_F (-1e10f)

typedef unsigned long long u64;

// Single fused kernel: 256 blocks x 1024 threads, one block per 16 output rows.
// All global loads are issued up-front into registers (single miss round),
// then processed. XCD-swizzled block ids give each XCD exactly one batch.
//   A) pack edges[b, 0:64, :] into 64x16 u64 bit-tile (16 int4/thread)
//   B) pack neighbor word0 (cols 0..63) for the block's 16 rows
//   C) batch column-max of features (8 float4/thread)
//   D) branchless OR-scan: row i saturated iff OR_{j in nb_i, j<64} tile[j] == ~0
//   E) saturated rows (prob ~1) broadcast colmax; else exact block-wide fallback.
__global__ __launch_bounds__(BLOCK) void fused_kernel(
        const float* __restrict__ feat,
        const int*   __restrict__ edges,
        float*       __restrict__ out) {
    // XCD-aware swizzle: hw blocks round-robin over 8 XCDs; logical blocks
    // 32x..32x+31 (one half-batch) land on XCD x.
    const int hw  = blockIdx.x;
    const int lb  = (hw & 7) * 32 + (hw >> 3);
    const int b   = lb >> 6;
    const int r0  = (lb & 63) * RPB;
    const int t   = threadIdx.x;
    const int lane = t & 63;
    const int wid  = t >> 6;            // 16 waves

    __shared__ u64   s_tile[64 * NWORDS];        // 8 KB packed edges[b, 0:64, :]
    __shared__ u64   s_nb[RPB];
    __shared__ int   s_need[RPB];
    __shared__ __align__(16) float4 s_red[128];  // 2 KB colmax partials
    // fallback-only:
    __shared__ int           s_ei[NN];
    __shared__ unsigned char s_reach[NN];
    __shared__ float s_m[BLOCK], s_u[BLOCK];

    if (t < RPB) s_need[t] = 0;

    const int*  eb = edges + (size_t)b * NN * NN;
    const int4* e4 = reinterpret_cast<const int4*>(eb);
    const float4* fb4 = reinterpret_cast<const float4*>(feat + (size_t)b * NN * DD);

    // ================= issue ALL global loads first =================
    // B: word0 load (threads 0..255 only)
    int4 vb;
    if (t < 256) {
        const int rr = t >> 4;          // 16 rows
        const int cc = t & 15;
        vb = e4[(size_t)(r0 + rr) * 256 + cc];
    }
    // A: tile rows. Wave wid handles rows j = p*16 + wid, p=0..3.
    // Lane c covers cols 16c..16c+15 of each row (4 int4).
    int4 va[4][4];
#pragma unroll
    for (int p = 0; p < 4; ++p) {
        const int j = p * 16 + wid;
#pragma unroll
        for (int q = 0; q < 4; ++q)
            va[p][q] = e4[(size_t)j * 256 + lane * 4 + q];
    }
    // C: features, 8 float4/thread, fully contiguous 16 KB sweeps
    float4 vc[8];
#pragma unroll
    for (int kk = 0; kk < 8; ++kk)
        vc[kk] = fb4[(size_t)kk * BLOCK + t];

    // ================= process =================
    // A: 16-bit chunk per (row, lane), OR across 4-lane groups, write u64 word
#pragma unroll
    for (int p = 0; p < 4; ++p) {
        const int j = p * 16 + wid;
        unsigned ch = 0;
#pragma unroll
        for (int q = 0; q < 4; ++q) {
            ch |= (va[p][q].x != 0 ? 1u : 0u) << (q * 4 + 0);
            ch |= (va[p][q].y != 0 ? 1u : 0u) << (q * 4 + 1);
            ch |= (va[p][q].z != 0 ? 1u : 0u) << (q * 4 + 2);
            ch |= (va[p][q].w != 0 ? 1u : 0u) << (q * 4 + 3);
        }
        u64 my = (u64)ch << ((lane & 3) * 16);
        my |= __shfl_xor(my, 1, 64);
        my |= __shfl_xor(my, 2, 64);
        if ((lane & 3) == 0) s_tile[j * NWORDS + (lane >> 2)] = my;
    }

    // B: pack word0 for my 16 rows
    if (t < 256) {
        const int rr = t >> 4;
        const int cc = t & 15;
        const unsigned nib = (vb.x != 0 ? 1u : 0u) | (vb.y != 0 ? 2u : 0u)
                           | (vb.z != 0 ? 4u : 0u) | (vb.w != 0 ? 8u : 0u);
        u64 my = (u64)nib << (cc * 4);
        my |= __shfl_xor(my, 1, 64);
        my |= __shfl_xor(my, 2, 64);
        my |= __shfl_xor(my, 4, 64);
        my |= __shfl_xor(my, 8, 64);
        if (cc == 0) s_nb[rr] = my;
    }

    // C: per-thread max, then wave-level shfl reduce over lanes sharing lane&7
    {
        float4 m = vc[0];
#pragma unroll
        for (int kk = 1; kk < 8; ++kk) {
            m.x = fmaxf(m.x, vc[kk].x); m.y = fmaxf(m.y, vc[kk].y);
            m.z = fmaxf(m.z, vc[kk].z); m.w = fmaxf(m.w, vc[kk].w);
        }
#pragma unroll
        for (int d = 8; d <= 32; d <<= 1) {
            m.x = fmaxf(m.x, __shfl_xor(m.x, d, 64));
            m.y = fmaxf(m.y, __shfl_xor(m.y, d, 64));
            m.z = fmaxf(m.z, __shfl_xor(m.z, d, 64));
            m.w = fmaxf(m.w, __shfl_xor(m.w, d, 64));
        }
        if (lane < 8) s_red[wid * 8 + lane] = m;   // 128 partials
    }
    __syncthreads();

    // D: branchless OR-scan (threads 0..255; one (row, word) each)
    const int il = t >> 4;
    const int w  = t & 15;
    if (t < 256) {
        const u64 nb = s_nb[il];
        u64 acc = 0ull;
#pragma unroll
        for (int j = 0; j < 64; ++j) {
            const u64 msk = 0ull - ((nb >> j) & 1ull);
            acc |= s_tile[j * NWORDS + w] & msk;
        }
        if (acc != ~0ull) atomicAdd(&s_need[il], 1);
    }
    // C-tree: 128 -> 8 float4 (index&7 preserved since s >= 8)
    for (int s = 64; s >= 8; s >>= 1) {
        __syncthreads();
        if (t < s) {
            float4 a = s_red[t];
            const float4 c = s_red[t + s];
            a.x = fmaxf(a.x, c.x); a.y = fmaxf(a.y, c.y);
            a.z = fmaxf(a.z, c.z); a.w = fmaxf(a.w, c.w);
            s_red[t] = a;
        }
    }
    __syncthreads();
    // s_red[0..7] = per-batch column max (32 floats)

    // E: fast path — broadcast colmax
    float* orow_base = out + (size_t)(b * NN + r0) * DD;
    if (t < 256 && s_need[il] == 0) {
        reinterpret_cast<float2*>(orow_base + il * DD)[w] =
            reinterpret_cast<const float2*>(s_red)[w];
    }

    bool any = false;
#pragma unroll
    for (int r = 0; r < RPB; ++r) any = any || (s_need[r] != 0);
    if (!any) return;

    // ---- exact fallback (prob ~0): full-j reachability straight from edges ----
    const float* fb = feat + (size_t)b * NN * DD;
    for (int r = 0; r < RPB; ++r) {
        if (s_need[r] == 0) continue;           // block-uniform
        const int i = r0 + r;
        const int* ei = eb + (size_t)i * NN;
        s_ei[t] = ei[t];
        __syncthreads();
        {
            const int k = t;
            int reach = 0;
            for (int j = 0; j < NN; ++j) {
                if (s_ei[j] != 0 && eb[(size_t)j * NN + k] != 0) { reach = 1; break; }
            }
            s_reach[k] = (unsigned char)reach;
        }
        __syncthreads();
        const int d  = t & 31;
        const int kc = t >> 5;                  // 32 chunks of 32 feature rows
        float mm = -INFINITY, um = -INFINITY;
        for (int kk = 0; kk < 32; ++kk) {
            const int k = kc * 32 + kk;
            const float f = fb[(size_t)k * DD + d];
            if (s_reach[k]) mm = fmaxf(mm, f); else um = fmaxf(um, f);
        }
        s_m[t] = mm; s_u[t] = um;
        __syncthreads();
        for (int s = 16; s > 0; s >>= 1) {
            if (kc < s) {
                s_m[kc * 32 + d] = fmaxf(s_m[kc * 32 + d], s_m[(kc + s) * 32 + d]);
                s_u[kc * 32 + d] = fmaxf(s_u[kc * 32 + d], s_u[(kc + s) * 32 + d]);
            }
            __syncthreads();
        }
        if (kc == 0)
            out[(size_t)(b * NN + i) * DD + d] = fmaxf(s_m[d], s_u[d] + NEG_INF_F);
        __syncthreads();
    }
}

extern "C" void kernel_launch(void* const* d_in, const int* in_sizes, int n_in,
                              void* d_out, int out_size, void* d_ws, size_t ws_size,
                              hipStream_t stream) {
    const float* feat  = (const float*)d_in[0];   // [B,N,D] f32
    const int*   edges = (const int*)d_in[1];     // [B,N,N] i32
    float*       out   = (float*)d_out;           // [B,N,D] f32
    (void)d_ws; (void)ws_size;

    fused_kernel<<<BB * 64, BLOCK, 0, stream>>>(feat, edges, out);
}

// Round 4
// 68.182 us; speedup vs baseline: 1.0538x; 1.0538x over previous
//
#include <hip/hip_runtime.h>
#include <cstdint>

#define BB 4
#define NN 1024
#define DD 32
#define NWORDS 16           // NN / 64
#define RPB 16              // rows per pool block
#define NEG_INF_F (-1e10f)

typedef unsigned long long u64;

// ws layout:
//   tile_ws : [BB][64][NWORDS] u64   (32 KB)  packed edges[b, 0:64, :]
//   word0_ws: [BB*NN] u64            (32 KB)  packed edges[row, 0:64]
//   cpart_ws: [BB][16][DD] f32       ( 8 KB)  colmax partials (64 rows each)
#define TILE_OFF  0
#define WORD0_OFF (BB * 64 * NWORDS)            // in u64 units
#define CPART_OFF ((BB * 64 * NWORDS + BB * NN) * 2)   // in f32 units (u64=2 f32)

// Kernel 1: all packing + colmax partials. Every thread issues exactly 1-2
// independent vector loads (no load feeding a cross-lane op) so nothing
// serializes on vmcnt. 576 blocks.
__global__ __launch_bounds__(256, 1) void prep_kernel(
        const float* __restrict__ feat,
        const int*   __restrict__ edges,
        u64*         __restrict__ ws64,
        float*       __restrict__ wsf) {
    const int blk = blockIdx.x;
    const int t   = threadIdx.x;

    __shared__ u64 s_word[NWORDS];
    __shared__ __align__(16) float4 s_red[32 * 8];

    if (blk < 256) {
        // ---- pack tile row: batch b = blk>>6, row rr = blk&63 ----
        // thread t covers columns 4t..4t+3 via one int4 load.
        const size_t grow = (size_t)(blk >> 6) * NN + (blk & 63);
        const int4 vv = reinterpret_cast<const int4*>(edges + grow * NN)[t];
        const unsigned nib = (vv.x != 0 ? 1u : 0u) | (vv.y != 0 ? 2u : 0u)
                           | (vv.z != 0 ? 4u : 0u) | (vv.w != 0 ? 8u : 0u);
        if (t < NWORDS) s_word[t] = 0ull;
        __syncthreads();
        atomicOr(&s_word[t >> 4], (u64)nib << ((t & 15) * 4));
        __syncthreads();
        if (t < NWORDS) ws64[TILE_OFF + blk * NWORDS + t] = s_word[t];
    } else if (blk < 512) {
        // ---- pack word0 (columns 0..63) for 16 rows ----
        const int idx  = blk - 256;             // 0..255
        const int grow = idx * 16 + (t >> 4);   // global row
        const int4 vv = reinterpret_cast<const int4*>(
            edges + (size_t)grow * NN)[t & 15];
        const unsigned nib = (vv.x != 0 ? 1u : 0u) | (vv.y != 0 ? 2u : 0u)
                           | (vv.z != 0 ? 4u : 0u) | (vv.w != 0 ? 8u : 0u);
        if (t < NWORDS) s_word[t] = 0ull;
        __syncthreads();
        atomicOr(&s_word[t >> 4], (u64)nib << ((t & 15) * 4));
        __syncthreads();
        if (t < NWORDS) ws64[WORD0_OFF + idx * 16 + t] = s_word[t];
    } else {
        // ---- colmax partial: p = blk-512 in [0,64); 64 feature rows ----
        const int p    = blk - 512;
        const int b    = p >> 4;
        const int part = p & 15;
        const float4* fb4 = reinterpret_cast<const float4*>(
            feat + (size_t)b * NN * DD);
        const int d4 = t & 7;
        const int kc = t >> 3;                  // 32 chunks of 2 rows
        float4 m = make_float4(-INFINITY, -INFINITY, -INFINITY, -INFINITY);
#pragma unroll
        for (int kk = 0; kk < 2; ++kk) {
            const float4 v2 = fb4[(size_t)(part * 64 + kc * 2 + kk) * 8 + d4];
            m.x = fmaxf(m.x, v2.x); m.y = fmaxf(m.y, v2.y);
            m.z = fmaxf(m.z, v2.z); m.w = fmaxf(m.w, v2.w);
        }
        s_red[kc * 8 + d4] = m;
        __syncthreads();
        for (int s = 16; s > 0; s >>= 1) {
            if (t < s * 8) {
                float4 a = s_red[t];
                const float4 c = s_red[t + s * 8];
                a.x = fmaxf(a.x, c.x); a.y = fmaxf(a.y, c.y);
                a.z = fmaxf(a.z, c.z); a.w = fmaxf(a.w, c.w);
                s_red[t] = a;
            }
            __syncthreads();
        }
        if (t < 8)
            reinterpret_cast<float4*>(wsf + CPART_OFF + (b * 16 + part) * DD)[t]
                = s_red[t];
    }
}

// Kernel 2: 256 blocks x 256 threads, 16 rows each.
// Branchless OR scan over the LDS tile; saturated words => colmax output.
// Exact fallback recomputes reachability straight from edges (prob ~0).
__global__ __launch_bounds__(256, 1) void pool_kernel(
        const float* __restrict__ feat,
        const int*   __restrict__ edges,
        const u64*   __restrict__ ws64,
        const float* __restrict__ wsf,
        float*       __restrict__ out) {
    const int blk = blockIdx.x;
    const int b   = blk >> 6;
    const int r0  = (blk & 63) * RPB;
    const int t   = threadIdx.x;
    const int il  = t >> 4;
    const int w   = t & 15;

    __shared__ __align__(16) u64 s_tile[64 * NWORDS];   // 8 KB
    __shared__ u64   s_rw[RPB];
    __shared__ int   s_need[RPB];
    __shared__ float s_part[256];
    // fallback-only:
    __shared__ int           s_ei[NN];
    __shared__ unsigned char s_reach[NN];
    __shared__ float s_m[256], s_u[256];

    if (t < RPB) s_need[t] = 0;

    // stage tile (8 KB) via two independent 16B loads per thread
    {
        const longlong2* tb = reinterpret_cast<const longlong2*>(
            ws64 + TILE_OFF + (size_t)b * 64 * NWORDS);
        reinterpret_cast<longlong2*>(s_tile)[t]       = tb[t];
        reinterpret_cast<longlong2*>(s_tile)[t + 256] = tb[t + 256];
    }
    // neighbor word0 for my 16 rows
    if (t < RPB) s_rw[t] = ws64[WORD0_OFF + b * NN + r0 + t];
    // colmax: reduce the 16 partials (512 floats) to 32
    {
        const float* cp = wsf + CPART_OFF + (size_t)b * 16 * DD;
        s_part[t] = fmaxf(cp[t], cp[t + 256]);
    }
    __syncthreads();
    for (int s = 128; s >= 32; s >>= 1) {
        if (t < s) s_part[t] = fmaxf(s_part[t], s_part[t + s]);
        __syncthreads();
    }
    // s_part[0..31] == per-batch column max

    // branchless OR scan: 64 independent LDS loads
    {
        const u64 nb = s_rw[il];
        u64 acc = 0ull;
#pragma unroll
        for (int j = 0; j < 64; ++j) {
            const u64 msk = 0ull - ((nb >> j) & 1ull);
            acc |= s_tile[j * NWORDS + w] & msk;
        }
        if (acc != ~0ull) atomicAdd(&s_need[il], 1);
    }
    __syncthreads();

    // fast path: broadcast colmax
    float* orow_base = out + (size_t)(b * NN + r0) * DD;
    if (s_need[il] == 0) {
        reinterpret_cast<float2*>(orow_base + il * DD)[w] =
            reinterpret_cast<const float2*>(s_part)[w];
    }

    bool any = false;
    for (int r = 0; r < RPB; ++r) any = any || (s_need[r] != 0);
    if (!any) return;

    // ---- exact fallback (prob ~0) ----
    const int* eb = edges + (size_t)b * NN * NN;
    for (int r = 0; r < RPB; ++r) {
        if (s_need[r] == 0) continue;           // block-uniform
        const int i = r0 + r;
        const int* ei = eb + (size_t)i * NN;
#pragma unroll
        for (int q = 0; q < 4; ++q) s_ei[t + q * 256] = ei[t + q * 256];
        __syncthreads();
#pragma unroll
        for (int kq = 0; kq < 4; ++kq) {
            const int k = t * 4 + kq;
            int reach = 0;
            for (int j = 0; j < NN; ++j) {
                if (s_ei[j] != 0 && eb[(size_t)j * NN + k] != 0) { reach = 1; break; }
            }
            s_reach[k] = (unsigned char)reach;
        }
        __syncthreads();
        const int d   = t & 31;
        const int kc8 = t >> 5;
        const float* fb = feat + (size_t)b * NN * DD;
        float mm = -INFINITY, um = -INFINITY;
        for (int kk = 0; kk < 128; ++kk) {
            const int k = kc8 * 128 + kk;
            const float f = fb[(size_t)k * DD + d];
            if (s_reach[k]) mm = fmaxf(mm, f); else um = fmaxf(um, f);
        }
        s_m[t] = mm; s_u[t] = um;
        __syncthreads();
        for (int s = 4; s > 0; s >>= 1) {
            if (kc8 < s) {
                s_m[kc8 * 32 + d] = fmaxf(s_m[kc8 * 32 + d], s_m[(kc8 + s) * 32 + d]);
                s_u[kc8 * 32 + d] = fmaxf(s_u[kc8 * 32 + d], s_u[(kc8 + s) * 32 + d]);
            }
            __syncthreads();
        }
        if (kc8 == 0)
            out[(size_t)(b * NN + i) * DD + d] = fmaxf(s_m[d], s_u[d] + NEG_INF_F);
        __syncthreads();
    }
}

extern "C" void kernel_launch(void* const* d_in, const int* in_sizes, int n_in,
                              void* d_out, int out_size, void* d_ws, size_t ws_size,
                              hipStream_t stream) {
    const float* feat  = (const float*)d_in[0];   // [B,N,D] f32
    const int*   edges = (const int*)d_in[1];     // [B,N,N] i32
    float*       out   = (float*)d_out;           // [B,N,D] f32
    u64*   ws64 = (u64*)d_ws;
    float* wsf  = (float*)d_ws;

    prep_kernel<<<576, 256, 0, stream>>>(feat, edges, ws64, wsf);
    pool_kernel<<<BB * NN / RPB, 256, 0, stream>>>(feat, edges, ws64, wsf, out);
}